// Round 17
// baseline (374.952 us; speedup 1.0000x reference)
//
#include <hip/hip_runtime.h>

// Soft product quantizer — two single-sweep MFMA kernels + precomputed tiles.
// z:(8,384,32,32) f32, C:(2048,384) f32. 4096 pairs (n,n+4096) x K=8, d=48, M=2048.
// s = 2<x,c> - |c|^2 (x^2 cancels; |s| small -> no max-subtract).
// prep: C -> bf16 tiles in ws (cs: [m][72] rows with -c2/2 at cols 48/49;
//       ct: transposed [d][72] per 64-code tile).
// K1 (stats): S-MFMA + exp2 -> Z, T2 (log2-domain) per row; LDS-atomic then
//       global-atomic into ws (each block covers a 1024-code half).
// K2 (out): recompute S, P=e (exp2), O = P*C (B-frags straight from ws, no ct
//       in LDS), cross-JSD in log2; O normalized in-block, atomicAdd to Out.
// Probe MFMAs label D-slots (mS=A-row, rS=B-col) -> correct for any bijective
// fragment layout. Out fully memset to 0 first (atomic accumulation target).

typedef __attribute__((ext_vector_type(8))) short short8;
typedef __attribute__((ext_vector_type(4))) float f32x4;

#define Z_BCH   (384*1024)
#define JSD_IDX 3145728
#define CS_TILE 9216
#define CT_TILE 6912
#define CT_OFF  2359296
#define ZS_OFF  4128768              // wsZ: 8*8192 f32
#define TS_OFF  (ZS_OFF + 262144)    // wsT2
#define KC      2.8853900817779268f  // 2*log2(e)
#define LN2     0.6931471805599453f

__device__ __forceinline__ f32x4 mfma32(short8 a, short8 b, f32x4 c) {
    return __builtin_amdgcn_mfma_f32_16x16x32_bf16(a, b, c, 0, 0, 0);
}
__device__ __forceinline__ unsigned short f2bf(float x) {
    unsigned u = __float_as_uint(x);
    u += 0x7FFF + ((u >> 16) & 1);
    return (unsigned short)(u >> 16);
}
__device__ __forceinline__ unsigned pk2bf(float a, float b) {
    return (unsigned)f2bf(a) | ((unsigned)f2bf(b) << 16);
}
__device__ __forceinline__ float bf2f(unsigned short h) {
    return __uint_as_float(((unsigned)h) << 16);
}

// ===================== prep: C -> bf16 tiles in ws =====================
__global__ __launch_bounds__(256)
void pq_prep(const float* __restrict__ Cb, unsigned char* __restrict__ ws)
{
    const int tid = threadIdx.x;
    const int k   = blockIdx.x >> 5;
    const int t   = blockIdx.x & 31;
    const int sm  = tid & 63, p8 = tid >> 6;
    const int m   = t*64 + sm;

    unsigned short* csT = (unsigned short*)(ws + (size_t)(k*32 + t)*CS_TILE);
    unsigned short* ctT = (unsigned short*)(ws + CT_OFF + (size_t)(k*32 + t)*CT_TILE);

    const float4* crow = (const float4*)(Cb + (size_t)m*384 + k*48);
    float4 va = crow[p8*3+0], vb = crow[p8*3+1], vc = crow[p8*3+2];
    const int d0 = p8*12;
    *(uint2*)(csT + sm*72 + d0 + 0) = make_uint2(pk2bf(va.x,va.y), pk2bf(va.z,va.w));
    *(uint2*)(csT + sm*72 + d0 + 4) = make_uint2(pk2bf(vb.x,vb.y), pk2bf(vb.z,vb.w));
    *(uint2*)(csT + sm*72 + d0 + 8) = make_uint2(pk2bf(vc.x,vc.y), pk2bf(vc.z,vc.w));
    ctT[(d0+ 0)*72+sm] = f2bf(va.x);  ctT[(d0+ 1)*72+sm] = f2bf(va.y);
    ctT[(d0+ 2)*72+sm] = f2bf(va.z);  ctT[(d0+ 3)*72+sm] = f2bf(va.w);
    ctT[(d0+ 4)*72+sm] = f2bf(vb.x);  ctT[(d0+ 5)*72+sm] = f2bf(vb.y);
    ctT[(d0+ 6)*72+sm] = f2bf(vb.z);  ctT[(d0+ 7)*72+sm] = f2bf(vb.w);
    ctT[(d0+ 8)*72+sm] = f2bf(vc.x);  ctT[(d0+ 9)*72+sm] = f2bf(vc.y);
    ctT[(d0+10)*72+sm] = f2bf(vc.z);  ctT[(d0+11)*72+sm] = f2bf(vc.w);
    if (tid < 64) {
        const float4* cr2 = (const float4*)(Cb + (size_t)(t*64 + tid)*384 + k*48);
        float c2 = 0.f;
#pragma unroll
        for (int i = 0; i < 12; ++i) {
            float4 v = cr2[i];
            c2 += v.x*v.x + v.y*v.y + v.z*v.z + v.w*v.w;
        }
        float mh = -0.5f*c2;
        unsigned short hi = f2bf(mh);
        unsigned short lo = f2bf(mh - bf2f(hi));
        *(uint2*)(csT + tid*72 + 48) = make_uint2((unsigned)hi | ((unsigned)lo << 16), 0u);
        *(uint2*)(csT + tid*72 + 52) = make_uint2(0u, 0u);
        *(uint2*)(csT + tid*72 + 56) = make_uint2(0u, 0u);
        *(uint2*)(csT + tid*72 + 60) = make_uint2(0u, 0u);
    }
}

// ---- shared decode/prolog pieces ----
#define PQ_DECODE                                                             \
    const int tid  = threadIdx.x;                                             \
    const int lane = tid & 63;                                                \
    const int wv   = tid >> 6;                                                \
    const int rg   = wv & 3;                                                  \
    const int chw  = wv >> 2;                                                 \
    const int lr   = lane & 15;                                               \
    const int lg   = lane >> 4;                                               \
    const int pg   = blockIdx.x & 63;                                         \
    const int half = (blockIdx.x >> 6) & 1;                                   \
    const int k    = blockIdx.x >> 7;                                         \
    const int t0   = half*16;

#define PQ_PROBES                                                             \
    short8 av, on;                                                            \
    _Pragma("unroll")                                                         \
    for (int i = 0; i < 8; ++i) { av[i] = (short)f2bf((float)lr); on[i] = (short)0x3F80; } \
    f32x4 zf4 = {0.f,0.f,0.f,0.f};                                            \
    f32x4 dmv = mfma32(av, on, zf4);                                          \
    f32x4 drv = mfma32(on, av, zf4);                                          \
    int mS[4], rS[4];                                                         \
    _Pragma("unroll")                                                         \
    for (int j = 0; j < 4; ++j) {                                             \
        mS[j] = ((int)(dmv[j]*0.03125f + 0.5f)) & 15;                         \
        rS[j] = ((int)(drv[j]*0.03125f + 0.5f)) & 15;                         \
    }

#define PQ_XFRAGS(Zin)                                                        \
    for (int i = tid; i < 6144; i += 512) {                                   \
        int row = i & 127, d = i >> 7;                                        \
        int n = pg*64 + (row & 63) + ((row & 64) ? 4096 : 0);                 \
        xs[row*72 + d] = f2bf(Zin[(size_t)(n >> 10)*Z_BCH + (k*48 + d)*1024 + (n & 1023)]); \
    }                                                                         \
    if (tid < 128) { xs[tid*72 + 48] = 0x3F80; xs[tid*72 + 49] = 0x3F80; }    \
    __syncthreads();                                                          \
    short8 xf[2][2];                                                          \
    _Pragma("unroll")                                                         \
    for (int kh = 0; kh < 2; ++kh) {                                          \
        xf[0][kh] = *(const short8*)(xs + (rg*16 + lr)*72 + kh*32 + lg*8);    \
        xf[1][kh] = *(const short8*)(xs + (64 + rg*16 + lr)*72 + kh*32 + lg*8); \
    }                                                                         \
    __syncthreads();

#define LOADREG(t) do {                                                       \
        const unsigned char* _c = csg + (size_t)(t)*CS_TILE;                  \
        r0 = *(const uint4*)(_c + tid*16);                                    \
        if (tid < 64) r1 = *(const uint4*)(_c + 8192 + tid*16);               \
    } while (0)
#define SWRITE(b) do {                                                        \
        *(uint4*)(smem + (b)*CS_TILE + tid*16) = r0;                          \
        if (tid < 64) *(uint4*)(smem + (b)*CS_TILE + 8192 + tid*16) = r1;     \
    } while (0)

// ===================== K1: stats (Z, T2 per row) =====================
// LDS: cs dbuf 18432 @0 | ztP/ttP/ztQ/ttQ 4x256 @18432 -> 19456. xs overlay @0.
__global__ __launch_bounds__(512, 8)
void pq_stats(const float* __restrict__ Zin, const unsigned char* __restrict__ ws,
              float* __restrict__ wsZ, float* __restrict__ wsT)
{
    __shared__ __align__(16) unsigned char smem[19456];
    unsigned short* xs = (unsigned short*)smem;
    float* ztP = (float*)(smem + 18432);
    float* ttP = (float*)(smem + 18688);
    float* ztQ = (float*)(smem + 18944);
    float* ttQ = (float*)(smem + 19200);

    PQ_DECODE
    PQ_PROBES
    const unsigned char* csg = ws + (size_t)(k*32)*CS_TILE;

    for (int i = tid; i < 4608; i += 512) ((unsigned*)smem)[i] = 0u;
    if (tid < 256) ((float*)(smem + 18432))[tid] = 0.f;
    __syncthreads();
    PQ_XFRAGS(Zin)

    uint4 r0, r1;
    float zp[4]={0,0,0,0}, tp[4]={0,0,0,0}, zq[4]={0,0,0,0}, tq[4]={0,0,0,0};

    LOADREG(t0);
    SWRITE(0);
    LOADREG(t0+1);
    __syncthreads();

#pragma unroll 1
    for (int t = 0; t < 16; ++t) {
        if (t < 15) SWRITE((t+1)&1);
        if (t < 14) LOADREG(t0+t+2);
        const unsigned short* cst = (const unsigned short*)(smem + (t&1)*CS_TILE);
#pragma unroll
        for (int lmt = 0; lmt < 2; ++lmt) {
            const int mt = chw*2 + lmt;
            short8 a0 = *(const short8*)(cst + (mt*16 + lr)*72 + lg*8);
            short8 a1 = *(const short8*)(cst + (mt*16 + lr)*72 + 32 + lg*8);
            f32x4 accP = {0.f,0.f,0.f,0.f}, accQ = {0.f,0.f,0.f,0.f};
            accP = mfma32(a0, xf[0][0], accP);
            accP = mfma32(a1, xf[0][1], accP);
            accQ = mfma32(a0, xf[1][0], accQ);
            accQ = mfma32(a1, xf[1][1], accQ);
#pragma unroll
            for (int j = 0; j < 4; ++j) {
                float s2p = accP[j]*KC, s2q = accQ[j]*KC;   // log2-domain
                float e1 = exp2f(s2p), e2 = exp2f(s2q);
                zp[j] += e1; tp[j] = fmaf(e1, s2p, tp[j]);
                zq[j] += e2; tq[j] = fmaf(e2, s2q, tq[j]);
            }
        }
        __syncthreads();
    }

#pragma unroll
    for (int j = 0; j < 4; ++j) {
        int r = rg*16 + rS[j];
        atomicAdd(ztP + r, zp[j]); atomicAdd(ttP + r, tp[j]);
        atomicAdd(ztQ + r, zq[j]); atomicAdd(ttQ + r, tq[j]);
    }
    __syncthreads();
    if (tid < 128) {   // global accumulate (2 half-blocks per row)
        int r = tid & 63;
        int n = pg*64 + r + ((tid & 64) ? 4096 : 0);
        float zv = (tid < 64) ? ztP[r] : ztQ[r];
        float tv = (tid < 64) ? ttP[r] : ttQ[r];
        atomicAdd(wsZ + (k << 13) + n, zv);
        atomicAdd(wsT + (k << 13) + n, tv);
    }
}

// ===================== K2: output (O, cross, store) =====================
// LDS: cs dbuf 18432 @0 | plds 8x2560 @18432 -> 38912 | ipz[128] @38912 |
// ent[128] @39424 | misc[8] @39936 -> 39968. xs overlay @0; obuf @0 epilogue.
__global__ __launch_bounds__(512, 6)
void pq_out(const float* __restrict__ Zin, const unsigned char* __restrict__ ws,
            const float* __restrict__ wsZ, const float* __restrict__ wsT,
            float* __restrict__ Out)
{
    __shared__ __align__(16) unsigned char smem[39968];
    unsigned short* xs = (unsigned short*)smem;
    float* ipz  = (float*)(smem + 38912);
    float* ent  = (float*)(smem + 39424);
    float* misc = (float*)(smem + 39936);
    float* obuf = (float*)smem;

    PQ_DECODE
    PQ_PROBES
    const bool packOK = __all(mS[1] == mS[0]+1 && mS[2] == mS[0]+2 && mS[3] == mS[0]+3
                              && rS[1] == rS[0] && rS[2] == rS[0] && rS[3] == rS[0]);
    const unsigned char* csg = ws + (size_t)(k*32)*CS_TILE;
    const unsigned char* ctg = ws + CT_OFF + (size_t)(k*32)*CT_TILE;
    unsigned short* plds = (unsigned short*)(smem + 18432 + wv*2560);   // [32][40]

    for (int i = tid; i < 4608; i += 512) ((unsigned*)smem)[i] = 0u;
    __syncthreads();
    PQ_XFRAGS(Zin)
    if (tid < 128) {   // per-row 1/Z and entropy (T2 in log2-units)
        int n = pg*64 + (tid & 63) + ((tid & 64) ? 4096 : 0);
        float Zr = wsZ[(k << 13) + n];
        float Tr = wsT[(k << 13) + n];
        float iz = 1.f / Zr;
        ipz[tid] = iz;
        ent[tid] = LN2*(Tr*iz) - __logf(Zr);
    }
    __syncthreads();
    float izp_s[4], izq_s[4];
#pragma unroll
    for (int j = 0; j < 4; ++j) {
        izp_s[j] = ipz[rg*16 + rS[j]];
        izq_s[j] = ipz[64 + rg*16 + rS[j]];
    }

    uint4 r0, r1;
    f32x4 Op[3], Oq[3];
#pragma unroll
    for (int dt = 0; dt < 3; ++dt) { Op[dt] = (f32x4){0.f,0.f,0.f,0.f}; Oq[dt] = (f32x4){0.f,0.f,0.f,0.f}; }
    float cross2 = 0.f;

    LOADREG(t0);
    SWRITE(0);
    LOADREG(t0+1);
    __syncthreads();

#pragma unroll 1
    for (int t = 0; t < 16; ++t) {
        if (t < 15) SWRITE((t+1)&1);
        if (t < 14) LOADREG(t0+t+2);
        // B-fragments for this tile straight from ws (L2-hot)
        const unsigned short* ctt = (const unsigned short*)(ctg + (size_t)(t0+t)*CT_TILE);
        short8 cB0 = *(const short8*)(ctt + (     lr)*72 + chw*32 + lg*8);
        short8 cB1 = *(const short8*)(ctt + (16 + lr)*72 + chw*32 + lg*8);
        short8 cB2 = *(const short8*)(ctt + (32 + lr)*72 + chw*32 + lg*8);
        const unsigned short* cst = (const unsigned short*)(smem + (t&1)*CS_TILE);
#pragma unroll
        for (int lmt = 0; lmt < 2; ++lmt) {
            const int mt = chw*2 + lmt;
            short8 a0 = *(const short8*)(cst + (mt*16 + lr)*72 + lg*8);
            short8 a1 = *(const short8*)(cst + (mt*16 + lr)*72 + 32 + lg*8);
            f32x4 accP = {0.f,0.f,0.f,0.f}, accQ = {0.f,0.f,0.f,0.f};
            accP = mfma32(a0, xf[0][0], accP);
            accP = mfma32(a1, xf[0][1], accP);
            accQ = mfma32(a0, xf[1][0], accQ);
            accQ = mfma32(a1, xf[1][1], accQ);
            float e1a[4], e2a[4];
#pragma unroll
            for (int j = 0; j < 4; ++j) {
                float e1 = exp2f(accP[j]*KC);
                float e2 = exp2f(accQ[j]*KC);
                e1a[j] = e1; e2a[j] = e2;
                float ss = fmaf(e1, izp_s[j], e2*izq_s[j]);
                cross2 = fmaf(ss, log2f(fmaf(0.5f, ss, 1e-12f)), cross2);
            }
            if (packOK) {
                *(uint2*)(plds + rS[0]*40        + lmt*16 + mS[0]) =
                    make_uint2(pk2bf(e1a[0], e1a[1]), pk2bf(e1a[2], e1a[3]));
                *(uint2*)(plds + (16 + rS[0])*40 + lmt*16 + mS[0]) =
                    make_uint2(pk2bf(e2a[0], e2a[1]), pk2bf(e2a[2], e2a[3]));
            } else {
#pragma unroll
                for (int j = 0; j < 4; ++j) {
                    plds[rS[j]*40        + lmt*16 + mS[j]] = f2bf(e1a[j]);
                    plds[(16 + rS[j])*40 + lmt*16 + mS[j]] = f2bf(e2a[j]);
                }
            }
        }
        {   // O = P*C (K=32, B-frags in registers)
            short8 pA = *(const short8*)(plds + lr*40        + lg*8);
            short8 qA = *(const short8*)(plds + (16 + lr)*40 + lg*8);
            Op[0] = mfma32(pA, cB0, Op[0]);
            Oq[0] = mfma32(qA, cB0, Oq[0]);
            Op[1] = mfma32(pA, cB1, Op[1]);
            Oq[1] = mfma32(qA, cB1, Oq[1]);
            Op[2] = mfma32(pA, cB2, Op[2]);
            Oq[2] = mfma32(qA, cB2, Oq[2]);
        }
        __syncthreads();
    }

    // ---------------- epilogue ----------------
#pragma unroll
    for (int off = 1; off < 64; off <<= 1) cross2 += __shfl_xor(cross2, off);
    if (lane == 0) misc[wv] = cross2;

    if (chw == 1) {
#pragma unroll
        for (int dt = 0; dt < 3; ++dt)
#pragma unroll
            for (int j = 0; j < 4; ++j) {
                obuf[(rg*32 +      mS[j])*48 + dt*16 + rS[j]] = Op[dt][j];
                obuf[(rg*32 + 16 + mS[j])*48 + dt*16 + rS[j]] = Oq[dt][j];
            }
    }
    __syncthreads();

    if (tid == 0) {
        float cr = 0.f;
        for (int w = 0; w < 8; ++w) cr += misc[w];
        float val = -LN2 * cr;
        if (half == 0) {
            float es = 0.f;
            for (int r = 0; r < 128; ++r) es += ent[r];
            val += es;
        }
        atomicAdd(Out + JSD_IDX, val * (0.5f/32768.f));
    }

    if (chw == 0) {   // combine chw halves, normalize, atomic-accumulate
#pragma unroll
        for (int dt = 0; dt < 3; ++dt)
#pragma unroll
            for (int j = 0; j < 4; ++j) {
                int xr = mS[j];
                int np = pg*64 + rg*16 + xr;
                int nq = np + 4096;
                int chc = k*48 + dt*16 + rS[j];
                float vP = (Op[dt][j] + obuf[(rg*32 +      xr)*48 + dt*16 + rS[j]]) * ipz[rg*16 + xr];
                float vQ = (Oq[dt][j] + obuf[(rg*32 + 16 + xr)*48 + dt*16 + rS[j]]) * ipz[64 + rg*16 + xr];
                atomicAdd(Out + (size_t)(np >> 10)*Z_BCH + (size_t)chc*1024 + (np & 1023), vP);
                atomicAdd(Out + (size_t)(nq >> 10)*Z_BCH + (size_t)chc*1024 + (nq & 1023), vQ);
            }
    }
}

extern "C" void kernel_launch(void* const* d_in, const int* in_sizes, int n_in,
                              void* d_out, int out_size, void* d_ws, size_t ws_size,
                              hipStream_t stream)
{
    const float* z = (const float*)d_in[0];
    const float* C = (const float*)d_in[1];
    float* out = (float*)d_out;
    unsigned char* ws = (unsigned char*)d_ws;
    float* wsZ = (float*)(ws + ZS_OFF);
    float* wsT = (float*)(ws + TS_OFF);

    // zero accumulation targets: full output + Z/T stats
    hipMemsetAsync(out, 0, (size_t)out_size*4, stream);
    hipMemsetAsync(ws + ZS_OFF, 0, 524288, stream);

    pq_prep <<<dim3(256),  dim3(256), 0, stream>>>(C, ws);
    pq_stats<<<dim3(1024), dim3(512), 0, stream>>>(z, ws, wsZ, wsT);
    pq_out  <<<dim3(1024), dim3(512), 0, stream>>>(z, ws, wsZ, wsT, out);
}

// Round 18
// 171.485 us; speedup vs baseline: 2.1865x; 2.1865x over previous
//
#include <hip/hip_runtime.h>

// Soft product quantizer — split stats/output kernels on the R16 structure.
// z:(8,384,32,32) f32, C:(2048,384) f32. 4096 pairs (n,n+4096) x K=8, d=48, M=2048.
// s = 2<x,c> - |c|^2 (x^2 cancels; |s| small -> no max-subtract).
// prep: C -> bf16 tiles in ws (cs rows with -c2/2 at cols 48/49; ct transposed).
// K1 (1024 blocks): S-MFMA + exp over a 1024-code half -> Z,T per row; LDS
//     atomics then global atomicAdd into wsZ/wsT.
// K2 (512 blocks): R16 pass-2 verbatim — recompute S, P scatter (probe coords),
//     O = P*C MFMA, cross-JSD; ipz/ent from wsZ/wsT; direct stores.
// Probe MFMAs label D-slots (mS=A-row, rS=B-col): correct under any bijective
// fragment layout.

typedef __attribute__((ext_vector_type(8))) short short8;
typedef __attribute__((ext_vector_type(4))) float f32x4;

#define Z_BCH   (384*1024)
#define JSD_IDX 3145728
#define CS_TILE 9216
#define CT_TILE 6912
#define CT_OFF  2359296
#define ZS_OFF  4128768              // wsZ: 8*8192 f32
#define TS_OFF  (ZS_OFF + 262144)    // wsT

__device__ __forceinline__ f32x4 mfma32(short8 a, short8 b, f32x4 c) {
    return __builtin_amdgcn_mfma_f32_16x16x32_bf16(a, b, c, 0, 0, 0);
}
__device__ __forceinline__ unsigned short f2bf(float x) {
    unsigned u = __float_as_uint(x);
    u += 0x7FFF + ((u >> 16) & 1);
    return (unsigned short)(u >> 16);
}
__device__ __forceinline__ unsigned pk2bf(float a, float b) {
    return (unsigned)f2bf(a) | ((unsigned)f2bf(b) << 16);
}
__device__ __forceinline__ float bf2f(unsigned short h) {
    return __uint_as_float(((unsigned)h) << 16);
}

// ===================== prep: C -> bf16 tiles in ws =====================
__global__ __launch_bounds__(256)
void pq_prep(const float* __restrict__ Cb, unsigned char* __restrict__ ws)
{
    const int tid = threadIdx.x;
    const int k   = blockIdx.x >> 5;
    const int t   = blockIdx.x & 31;
    const int sm  = tid & 63, p8 = tid >> 6;
    const int m   = t*64 + sm;

    unsigned short* csT = (unsigned short*)(ws + (size_t)(k*32 + t)*CS_TILE);
    unsigned short* ctT = (unsigned short*)(ws + CT_OFF + (size_t)(k*32 + t)*CT_TILE);

    const float4* crow = (const float4*)(Cb + (size_t)m*384 + k*48);
    float4 va = crow[p8*3+0], vb = crow[p8*3+1], vc = crow[p8*3+2];
    const int d0 = p8*12;
    *(uint2*)(csT + sm*72 + d0 + 0) = make_uint2(pk2bf(va.x,va.y), pk2bf(va.z,va.w));
    *(uint2*)(csT + sm*72 + d0 + 4) = make_uint2(pk2bf(vb.x,vb.y), pk2bf(vb.z,vb.w));
    *(uint2*)(csT + sm*72 + d0 + 8) = make_uint2(pk2bf(vc.x,vc.y), pk2bf(vc.z,vc.w));
    ctT[(d0+ 0)*72+sm] = f2bf(va.x);  ctT[(d0+ 1)*72+sm] = f2bf(va.y);
    ctT[(d0+ 2)*72+sm] = f2bf(va.z);  ctT[(d0+ 3)*72+sm] = f2bf(va.w);
    ctT[(d0+ 4)*72+sm] = f2bf(vb.x);  ctT[(d0+ 5)*72+sm] = f2bf(vb.y);
    ctT[(d0+ 6)*72+sm] = f2bf(vb.z);  ctT[(d0+ 7)*72+sm] = f2bf(vb.w);
    ctT[(d0+ 8)*72+sm] = f2bf(vc.x);  ctT[(d0+ 9)*72+sm] = f2bf(vc.y);
    ctT[(d0+10)*72+sm] = f2bf(vc.z);  ctT[(d0+11)*72+sm] = f2bf(vc.w);
    if (tid < 64) {
        const float4* cr2 = (const float4*)(Cb + (size_t)(t*64 + tid)*384 + k*48);
        float c2 = 0.f;
#pragma unroll
        for (int i = 0; i < 12; ++i) {
            float4 v = cr2[i];
            c2 += v.x*v.x + v.y*v.y + v.z*v.z + v.w*v.w;
        }
        float mh = -0.5f*c2;
        unsigned short hi = f2bf(mh);
        unsigned short lo = f2bf(mh - bf2f(hi));
        *(uint2*)(csT + tid*72 + 48) = make_uint2((unsigned)hi | ((unsigned)lo << 16), 0u);
        *(uint2*)(csT + tid*72 + 52) = make_uint2(0u, 0u);
        *(uint2*)(csT + tid*72 + 56) = make_uint2(0u, 0u);
        *(uint2*)(csT + tid*72 + 60) = make_uint2(0u, 0u);
    }
}

// ---- shared pieces ----
#define PQ_PROBES                                                             \
    short8 av, on;                                                            \
    _Pragma("unroll")                                                         \
    for (int i = 0; i < 8; ++i) { av[i] = (short)f2bf((float)lr); on[i] = (short)0x3F80; } \
    f32x4 zf4 = {0.f,0.f,0.f,0.f};                                            \
    f32x4 dmv = mfma32(av, on, zf4);                                          \
    f32x4 drv = mfma32(on, av, zf4);                                          \
    int mS[4], rS[4];                                                         \
    _Pragma("unroll")                                                         \
    for (int j = 0; j < 4; ++j) {                                             \
        mS[j] = ((int)(dmv[j]*0.03125f + 0.5f)) & 15;                         \
        rS[j] = ((int)(drv[j]*0.03125f + 0.5f)) & 15;                         \
    }

#define PQ_XFRAGS(Zin)                                                        \
    for (int i = tid; i < 6144; i += 512) {                                   \
        int row = i & 127, d = i >> 7;                                        \
        int n = pg*64 + (row & 63) + ((row & 64) ? 4096 : 0);                 \
        xs[row*72 + d] = f2bf(Zin[(size_t)(n >> 10)*Z_BCH + (k*48 + d)*1024 + (n & 1023)]); \
    }                                                                         \
    if (tid < 128) { xs[tid*72 + 48] = 0x3F80; xs[tid*72 + 49] = 0x3F80; }    \
    __syncthreads();                                                          \
    short8 xf[2][2];                                                          \
    _Pragma("unroll")                                                         \
    for (int kh = 0; kh < 2; ++kh) {                                          \
        xf[0][kh] = *(const short8*)(xs + (rg*16 + lr)*72 + kh*32 + lg*8);    \
        xf[1][kh] = *(const short8*)(xs + (64 + rg*16 + lr)*72 + kh*32 + lg*8); \
    }                                                                         \
    __syncthreads();

#define LOADREG(t) do {                                                       \
        const unsigned char* _c = csg + (size_t)(t)*CS_TILE;                  \
        r0 = *(const uint4*)(_c + tid*16);                                    \
        if (tid < 64) r1 = *(const uint4*)(_c + 8192 + tid*16);               \
    } while (0)
#define SWRITE(b) do {                                                        \
        *(uint4*)(smem + (b)*CS_TILE + tid*16) = r0;                          \
        if (tid < 64) *(uint4*)(smem + (b)*CS_TILE + 8192 + tid*16) = r1;     \
    } while (0)
#define LOADREG_CT(t) do {                                                    \
        LOADREG(t);                                                           \
        if (tid < 432) r2 = *(const uint4*)(ctg + (size_t)(t)*CT_TILE + tid*16); \
    } while (0)
#define SWRITE_CT(b) do {                                                     \
        SWRITE(b);                                                            \
        if (tid < 432) *(uint4*)(smem + 18432 + (b)*CT_TILE + tid*16) = r2;   \
    } while (0)

// ===================== K1: stats (1024 blocks, code-half each) =====================
// LDS: cs dbuf 18432 @0 | ztP/ttP/ztQ/ttQ 4x256 @18432 -> 19456. xs overlay @0.
__global__ __launch_bounds__(512, 4)
void pq_stats(const float* __restrict__ Zin, const unsigned char* __restrict__ ws,
              float* __restrict__ wsZ, float* __restrict__ wsT)
{
    __shared__ __align__(16) unsigned char smem[19456];
    unsigned short* xs = (unsigned short*)smem;
    float* ztP = (float*)(smem + 18432);
    float* ttP = (float*)(smem + 18688);
    float* ztQ = (float*)(smem + 18944);
    float* ttQ = (float*)(smem + 19200);

    const int tid  = threadIdx.x;
    const int lane = tid & 63;
    const int wv   = tid >> 6;
    const int rg   = wv & 3;
    const int chw  = wv >> 2;
    const int lr   = lane & 15;
    const int lg   = lane >> 4;
    const int pg   = blockIdx.x & 63;
    const int half = (blockIdx.x >> 6) & 1;
    const int k    = blockIdx.x >> 7;
    const int t0   = half*16;

    PQ_PROBES
    const unsigned char* csg = ws + (size_t)(k*32)*CS_TILE;

    for (int i = tid; i < 4608; i += 512) ((unsigned*)smem)[i] = 0u;
    if (tid < 256) ((float*)(smem + 18432))[tid] = 0.f;
    __syncthreads();
    PQ_XFRAGS(Zin)

    uint4 r0, r1;
    float zp[4]={0,0,0,0}, tp[4]={0,0,0,0}, zq[4]={0,0,0,0}, tq[4]={0,0,0,0};

    LOADREG(t0);
    SWRITE(0);
    LOADREG(t0+1);
    __syncthreads();

#pragma unroll 1
    for (int t = 0; t < 16; ++t) {
        if (t < 15) SWRITE((t+1)&1);
        if (t < 14) LOADREG(t0+t+2);
        const unsigned short* cst = (const unsigned short*)(smem + (t&1)*CS_TILE);
#pragma unroll
        for (int lmt = 0; lmt < 2; ++lmt) {
            const int mt = chw*2 + lmt;
            short8 a0 = *(const short8*)(cst + (mt*16 + lr)*72 + lg*8);
            short8 a1 = *(const short8*)(cst + (mt*16 + lr)*72 + 32 + lg*8);
            f32x4 accP = {0.f,0.f,0.f,0.f}, accQ = {0.f,0.f,0.f,0.f};
            accP = mfma32(a0, xf[0][0], accP);
            accP = mfma32(a1, xf[0][1], accP);
            accQ = mfma32(a0, xf[1][0], accQ);
            accQ = mfma32(a1, xf[1][1], accQ);
#pragma unroll
            for (int j = 0; j < 4; ++j) {
                float sp = 2.f*accP[j], sq = 2.f*accQ[j];
                float e1 = __expf(sp), e2 = __expf(sq);
                zp[j] += e1; tp[j] = fmaf(e1, sp, tp[j]);
                zq[j] += e2; tq[j] = fmaf(e2, sq, tq[j]);
            }
        }
        __syncthreads();
    }

#pragma unroll
    for (int j = 0; j < 4; ++j) {
        int r = rg*16 + rS[j];
        atomicAdd(ztP + r, zp[j]); atomicAdd(ttP + r, tp[j]);
        atomicAdd(ztQ + r, zq[j]); atomicAdd(ttQ + r, tq[j]);
    }
    __syncthreads();
    if (tid < 128) {
        int r = tid & 63;
        int n = pg*64 + r + ((tid & 64) ? 4096 : 0);
        float zv = (tid < 64) ? ztP[r] : ztQ[r];
        float tv = (tid < 64) ? ttP[r] : ttQ[r];
        atomicAdd(wsZ + (k << 13) + n, zv);
        atomicAdd(wsT + (k << 13) + n, tv);
    }
}

// ===================== K2: output (512 blocks, all codes) =====================
// LDS: cs dbuf 18432 @0 | ct dbuf 13824 @18432 | plds 8x2560 @32256 ->52736 |
// ipz[128] @52736 | ent[128] @53248 | misc[8] @53760 -> 53792.
// xs overlay @0; obuf[4][32][48] f32 @0 epilogue.
__global__ __launch_bounds__(512, 4)
void pq_out(const float* __restrict__ Zin, const unsigned char* __restrict__ ws,
            const float* __restrict__ wsZ, const float* __restrict__ wsT,
            float* __restrict__ Out)
{
    __shared__ __align__(16) unsigned char smem[53792];
    unsigned short* xs = (unsigned short*)smem;
    float* ipz  = (float*)(smem + 52736);
    float* ent  = (float*)(smem + 53248);
    float* misc = (float*)(smem + 53760);
    float* obuf = (float*)smem;

    const int tid  = threadIdx.x;
    const int lane = tid & 63;
    const int wv   = tid >> 6;
    const int rg   = wv & 3;
    const int chw  = wv >> 2;
    const int lr   = lane & 15;
    const int lg   = lane >> 4;
    const int pg   = blockIdx.x & 63;
    const int k    = blockIdx.x >> 6;

    PQ_PROBES
    const bool packOK = __all(mS[1] == mS[0]+1 && mS[2] == mS[0]+2 && mS[3] == mS[0]+3
                              && rS[1] == rS[0] && rS[2] == rS[0] && rS[3] == rS[0]);
    const unsigned char* csg = ws + (size_t)(k*32)*CS_TILE;
    const unsigned char* ctg = ws + CT_OFF + (size_t)(k*32)*CT_TILE;
    unsigned short* plds = (unsigned short*)(smem + 32256 + wv*2560);   // [32][40]

    for (int i = tid; i < 4608; i += 512) ((unsigned*)smem)[i] = 0u;
    __syncthreads();
    PQ_XFRAGS(Zin)
    if (tid < 128) {
        int n = pg*64 + (tid & 63) + ((tid & 64) ? 4096 : 0);
        float Zr = wsZ[(k << 13) + n];
        float Tr = wsT[(k << 13) + n];
        float iz = 1.f / Zr;
        ipz[tid] = iz;
        ent[tid] = Tr*iz - __logf(Zr);
    }
    __syncthreads();
    float izp_s[4], izq_s[4];
#pragma unroll
    for (int j = 0; j < 4; ++j) {
        izp_s[j] = ipz[rg*16 + rS[j]];
        izq_s[j] = ipz[64 + rg*16 + rS[j]];
    }

    uint4 r0, r1, r2;
    f32x4 Op[3], Oq[3];
#pragma unroll
    for (int dt = 0; dt < 3; ++dt) { Op[dt] = (f32x4){0.f,0.f,0.f,0.f}; Oq[dt] = (f32x4){0.f,0.f,0.f,0.f}; }
    float cross = 0.f;

    LOADREG_CT(0);
    SWRITE_CT(0);
    LOADREG_CT(1);
    __syncthreads();

#pragma unroll 1
    for (int t = 0; t < 32; ++t) {
        if (t < 31) SWRITE_CT((t+1)&1);
        if (t < 30) LOADREG_CT(t+2);
        const unsigned short* cst = (const unsigned short*)(smem + (t&1)*CS_TILE);
        const unsigned short* ctt = (const unsigned short*)(smem + 18432 + (t&1)*CT_TILE);
#pragma unroll
        for (int lmt = 0; lmt < 2; ++lmt) {
            const int mt = chw*2 + lmt;
            short8 a0 = *(const short8*)(cst + (mt*16 + lr)*72 + lg*8);
            short8 a1 = *(const short8*)(cst + (mt*16 + lr)*72 + 32 + lg*8);
            f32x4 accP = {0.f,0.f,0.f,0.f}, accQ = {0.f,0.f,0.f,0.f};
            accP = mfma32(a0, xf[0][0], accP);
            accP = mfma32(a1, xf[0][1], accP);
            accQ = mfma32(a0, xf[1][0], accQ);
            accQ = mfma32(a1, xf[1][1], accQ);
            float e1a[4], e2a[4];
#pragma unroll
            for (int j = 0; j < 4; ++j) {
                float e1 = __expf(2.f*accP[j]);
                float e2 = __expf(2.f*accQ[j]);
                e1a[j] = e1; e2a[j] = e2;
                float ss = fmaf(e1, izp_s[j], e2*izq_s[j]);
                cross = fmaf(ss, __logf(fmaf(0.5f, ss, 1e-12f)), cross);
            }
            if (packOK) {
                *(uint2*)(plds + rS[0]*40        + lmt*16 + mS[0]) =
                    make_uint2(pk2bf(e1a[0], e1a[1]), pk2bf(e1a[2], e1a[3]));
                *(uint2*)(plds + (16 + rS[0])*40 + lmt*16 + mS[0]) =
                    make_uint2(pk2bf(e2a[0], e2a[1]), pk2bf(e2a[2], e2a[3]));
            } else {
#pragma unroll
                for (int j = 0; j < 4; ++j) {
                    plds[rS[j]*40        + lmt*16 + mS[j]] = f2bf(e1a[j]);
                    plds[(16 + rS[j])*40 + lmt*16 + mS[j]] = f2bf(e2a[j]);
                }
            }
        }
        {
            short8 pA = *(const short8*)(plds + lr*40        + lg*8);
            short8 qA = *(const short8*)(plds + (16 + lr)*40 + lg*8);
#pragma unroll
            for (int dt = 0; dt < 3; ++dt) {
                short8 cB = *(const short8*)(ctt + (dt*16 + lr)*72 + chw*32 + lg*8);
                Op[dt] = mfma32(pA, cB, Op[dt]);
                Oq[dt] = mfma32(qA, cB, Oq[dt]);
            }
        }
        __syncthreads();
    }

    // ---------------- epilogue ----------------
#pragma unroll
    for (int off = 1; off < 64; off <<= 1) cross += __shfl_xor(cross, off);
    if (lane == 0) misc[wv] = cross;

    if (chw == 1) {
#pragma unroll
        for (int dt = 0; dt < 3; ++dt)
#pragma unroll
            for (int j = 0; j < 4; ++j) {
                obuf[(rg*32 +      mS[j])*48 + dt*16 + rS[j]] = Op[dt][j];
                obuf[(rg*32 + 16 + mS[j])*48 + dt*16 + rS[j]] = Oq[dt][j];
            }
    }
    __syncthreads();

    if (tid == 0) {
        float es = 0.f;
        for (int r = 0; r < 128; ++r) es += ent[r];
        float cr = 0.f;
        for (int w = 0; w < 8; ++w) cr += misc[w];
        atomicAdd(Out + JSD_IDX, (es - cr) * (0.5f/32768.f));
    }

    if (chw == 0) {
#pragma unroll
        for (int dt = 0; dt < 3; ++dt)
#pragma unroll
            for (int j = 0; j < 4; ++j) {
                int xr = mS[j];
                int np = pg*64 + rg*16 + xr;
                int nq = np + 4096;
                int chc = k*48 + dt*16 + rS[j];
                float vP = (Op[dt][j] + obuf[(rg*32 +      xr)*48 + dt*16 + rS[j]]) * ipz[rg*16 + xr];
                float vQ = (Oq[dt][j] + obuf[(rg*32 + 16 + xr)*48 + dt*16 + rS[j]]) * ipz[64 + rg*16 + xr];
                Out[(size_t)(np >> 10)*Z_BCH + (size_t)chc*1024 + (np & 1023)] = vP;
                Out[(size_t)(nq >> 10)*Z_BCH + (size_t)chc*1024 + (nq & 1023)] = vQ;
            }
    }
}

extern "C" void kernel_launch(void* const* d_in, const int* in_sizes, int n_in,
                              void* d_out, int out_size, void* d_ws, size_t ws_size,
                              hipStream_t stream)
{
    const float* z = (const float*)d_in[0];
    const float* C = (const float*)d_in[1];
    float* out = (float*)d_out;
    unsigned char* ws = (unsigned char*)d_ws;
    float* wsZ = (float*)(ws + ZS_OFF);
    float* wsT = (float*)(ws + TS_OFF);

    hipMemsetAsync(out + JSD_IDX, 0, sizeof(float), stream);
    hipMemsetAsync(ws + ZS_OFF, 0, 524288, stream);

    pq_prep <<<dim3(256),  dim3(256), 0, stream>>>(C, ws);
    pq_stats<<<dim3(1024), dim3(512), 0, stream>>>(z, ws, wsZ, wsT);
    pq_out  <<<dim3(512),  dim3(512), 0, stream>>>(z, ws, wsZ, wsT, out);
}